// Round 5
// baseline (1648.194 us; speedup 1.0000x reference)
//
#include <hip/hip_runtime.h>

// ==================== degree ====================

__global__ void count_deg(const int* __restrict__ dst, int* __restrict__ cnt, int E) {
    int e = blockIdx.x * blockDim.x + threadIdx.x;
    if (e < E) atomicAdd(&cnt[dst[e]], 1);
}

__global__ void deg_to_dis(const int* __restrict__ cnt, float* __restrict__ dis, int n) {
    int i = blockIdx.x * blockDim.x + threadIdx.x;
    if (i < n) dis[i] = rsqrtf((float)cnt[i] + 1.0f);
}

// ==================== bucket binning ====================
// bucket = dst >> 7 (128 nodes per bucket). NB <= 1024 assumed (n <= 131072).
#define BKT_SHIFT 7
#define BKT_NODES 128
#define CHUNK 16384  // edges per hist/scatter block (512 thr x 32)

__global__ __launch_bounds__(512) void hist_k(const int* __restrict__ dst, int* __restrict__ histG,
                                              int B, int NB, int E) {
    __shared__ int hist[1024];
    int tid = threadIdx.x;
    for (int i = tid; i < NB; i += 512) hist[i] = 0;
    __syncthreads();
    int base = blockIdx.x * CHUNK;
    for (int i = tid; i < CHUNK; i += 512) {
        int e = base + i;
        if (e >= E) break;
        atomicAdd(&hist[dst[e] >> BKT_SHIFT], 1);
    }
    __syncthreads();
    for (int i = tid; i < NB; i += 512) histG[(size_t)i * B + blockIdx.x] = hist[i];
}

__global__ __launch_bounds__(512) void scatter_k(const int* __restrict__ src, const int* __restrict__ dst,
                                                 const int* __restrict__ scanG, int* __restrict__ pairs,
                                                 int B, int NB, int E) {
    __shared__ int sbase[1024];
    __shared__ int scnt[1024];
    int tid = threadIdx.x;
    for (int i = tid; i < NB; i += 512) {
        sbase[i] = scanG[(size_t)i * B + blockIdx.x];
        scnt[i] = 0;
    }
    __syncthreads();
    int base = blockIdx.x * CHUNK;
    for (int i = tid; i < CHUNK; i += 512) {
        int e = base + i;
        if (e >= E) break;
        int d = dst[e], s = src[e];
        int b = d >> BKT_SHIFT;
        int r = atomicAdd(&scnt[b], 1);
        pairs[sbase[b] + r] = (s << BKT_SHIFT) | (d & (BKT_NODES - 1));
    }
}

// ==================== scan (exclusive), 256 thr x 8 = 2048 elems/block ====================
#define SCAN_VPT 8
#define SCAN_ELEMS 2048

__global__ __launch_bounds__(256) void scan1(const int* __restrict__ in, int* __restrict__ out,
                                             int* __restrict__ blksum, int n) {
    __shared__ int sh[256];
    int base = blockIdx.x * SCAN_ELEMS + threadIdx.x * SCAN_VPT;
    int v[SCAN_VPT];
    int sum = 0;
    #pragma unroll
    for (int j = 0; j < SCAN_VPT; ++j) {
        v[j] = (base + j < n) ? in[base + j] : 0;
        sum += v[j];
    }
    sh[threadIdx.x] = sum;
    __syncthreads();
    for (int off = 1; off < 256; off <<= 1) {
        int t = (threadIdx.x >= off) ? sh[threadIdx.x - off] : 0;
        __syncthreads();
        sh[threadIdx.x] += t;
        __syncthreads();
    }
    if (threadIdx.x == 255) blksum[blockIdx.x] = sh[255];
    int run = sh[threadIdx.x] - sum;  // exclusive within block
    #pragma unroll
    for (int j = 0; j < SCAN_VPT; ++j) {
        if (base + j < n) out[base + j] = run;
        run += v[j];
    }
}

__global__ __launch_bounds__(256) void scan2(int* __restrict__ blksum, int nb) {
    __shared__ int sh[256];
    int t = threadIdx.x;
    int v = (t < nb) ? blksum[t] : 0;
    sh[t] = v;
    __syncthreads();
    for (int off = 1; off < 256; off <<= 1) {
        int u = (t >= off) ? sh[t - off] : 0;
        __syncthreads();
        sh[t] += u;
        __syncthreads();
    }
    if (t < nb) blksum[t] = sh[t] - v;  // exclusive
}

__global__ void scan3(int* __restrict__ out, const int* __restrict__ blksum, int n) {
    int i = blockIdx.x * blockDim.x + threadIdx.x;
    if (i < n) out[i] += blksum[i >> 11];  // i / SCAN_ELEMS
}

// ==================== GEMMs (epilogue scales row by dis[node] -> g) ====================

__global__ __launch_bounds__(128) void gemm1(const float* __restrict__ x, const float* __restrict__ W,
                                             const float* __restrict__ dis, float* __restrict__ g, int n) {
    __shared__ float ws[32 * 32];
    __shared__ float xs[128][33];
    int tid = threadIdx.x;
    int node0 = blockIdx.x * 128;
    int node = node0 + tid;
    float acc[32];
    #pragma unroll
    for (int c = 0; c < 32; ++c) acc[c] = 0.f;

    for (int k0 = 0; k0 < 512; k0 += 32) {
        __syncthreads();
        #pragma unroll
        for (int r = 0; r < 2; ++r) {
            int fi = tid + r * 128;
            int k = fi >> 3, c4 = fi & 7;
            float4 wv = *(const float4*)(W + (size_t)(k0 + k) * 32 + c4 * 4);
            *((float4*)(ws + k * 32 + c4 * 4)) = wv;
        }
        #pragma unroll
        for (int r = 0; r < 8; ++r) {
            int fi = tid + r * 128;
            int nd = fi >> 3, k4 = fi & 7;
            int gn = min(node0 + nd, n - 1);
            float4 xv = *(const float4*)(x + (size_t)gn * 512 + k0 + k4 * 4);
            xs[nd][k4 * 4 + 0] = xv.x;
            xs[nd][k4 * 4 + 1] = xv.y;
            xs[nd][k4 * 4 + 2] = xv.z;
            xs[nd][k4 * 4 + 3] = xv.w;
        }
        __syncthreads();
        #pragma unroll
        for (int k = 0; k < 32; ++k) {
            float xv = xs[tid][k];
            #pragma unroll
            for (int c = 0; c < 32; ++c) acc[c] += xv * ws[k * 32 + c];
        }
    }
    if (node < n) {
        float dv = dis[node];
        float4* out4 = (float4*)(g + (size_t)node * 32);
        #pragma unroll
        for (int c4 = 0; c4 < 8; ++c4)
            out4[c4] = make_float4(acc[c4 * 4] * dv, acc[c4 * 4 + 1] * dv,
                                   acc[c4 * 4 + 2] * dv, acc[c4 * 4 + 3] * dv);
    }
}

__global__ __launch_bounds__(128) void gemm2(const float* __restrict__ xin, const float* __restrict__ W,
                                             const float* __restrict__ dis, float* __restrict__ g, int n) {
    __shared__ float ws[32 * 16];
    __shared__ float xs[128][33];
    int tid = threadIdx.x;
    int node0 = blockIdx.x * 128;
    int node = node0 + tid;
    {
        int k = tid >> 2, c4 = tid & 3;
        float4 wv = *(const float4*)(W + (size_t)k * 16 + c4 * 4);
        *((float4*)(ws + k * 16 + c4 * 4)) = wv;
    }
    #pragma unroll
    for (int r = 0; r < 8; ++r) {
        int fi = tid + r * 128;
        int nd = fi >> 3, k4 = fi & 7;
        int gn = min(node0 + nd, n - 1);
        float4 xv = *(const float4*)(xin + (size_t)gn * 32 + k4 * 4);
        xs[nd][k4 * 4 + 0] = xv.x;
        xs[nd][k4 * 4 + 1] = xv.y;
        xs[nd][k4 * 4 + 2] = xv.z;
        xs[nd][k4 * 4 + 3] = xv.w;
    }
    __syncthreads();
    float acc[16];
    #pragma unroll
    for (int c = 0; c < 16; ++c) acc[c] = 0.f;
    #pragma unroll
    for (int k = 0; k < 32; ++k) {
        float xv = xs[tid][k];
        #pragma unroll
        for (int c = 0; c < 16; ++c) acc[c] += xv * ws[k * 16 + c];
    }
    if (node < n) {
        float dv = dis[node];
        float4* out4 = (float4*)(g + (size_t)node * 16);
        #pragma unroll
        for (int c4 = 0; c4 < 4; ++c4)
            out4[c4] = make_float4(acc[c4 * 4] * dv, acc[c4 * 4 + 1] * dv,
                                   acc[c4 * 4 + 2] * dv, acc[c4 * 4 + 3] * dv);
    }
}

__global__ __launch_bounds__(128) void gemm3(const float* __restrict__ xin, const float* __restrict__ W,
                                             const float* __restrict__ dis, float* __restrict__ g, int n) {
    __shared__ float ws[16 * 16];
    __shared__ float xs[128][17];
    int tid = threadIdx.x;
    int node0 = blockIdx.x * 128;
    int node = node0 + tid;
    #pragma unroll
    for (int fi = 0; fi < 2; ++fi) {
        int i = tid + fi * 128;
        int k = i >> 4, c = i & 15;
        ws[i] = (c < 11) ? W[(size_t)k * 11 + c] : 0.f;
    }
    #pragma unroll
    for (int r = 0; r < 4; ++r) {
        int fi = tid + r * 128;
        int nd = fi >> 2, k4 = fi & 3;
        int gn = min(node0 + nd, n - 1);
        float4 xv = *(const float4*)(xin + (size_t)gn * 16 + k4 * 4);
        xs[nd][k4 * 4 + 0] = xv.x;
        xs[nd][k4 * 4 + 1] = xv.y;
        xs[nd][k4 * 4 + 2] = xv.z;
        xs[nd][k4 * 4 + 3] = xv.w;
    }
    __syncthreads();
    float acc[16];
    #pragma unroll
    for (int c = 0; c < 16; ++c) acc[c] = 0.f;
    #pragma unroll
    for (int k = 0; k < 16; ++k) {
        float xv = xs[tid][k];
        #pragma unroll
        for (int c = 0; c < 16; ++c) acc[c] += xv * ws[k * 16 + c];
    }
    if (node < n) {
        float dv = dis[node];
        float4* out4 = (float4*)(g + (size_t)node * 16);
        #pragma unroll
        for (int c4 = 0; c4 < 4; ++c4)
            out4[c4] = make_float4(acc[c4 * 4] * dv, acc[c4 * 4 + 1] * dv,
                                   acc[c4 * 4 + 2] * dv, acc[c4 * 4 + 3] * dv);
    }
}

// ==================== bucket gather: LDS agg + fused self-loop/bias/relu ====================
// One block (512 thr = 8 waves) per bucket of 128 dst nodes.
// key = (src << 7) | dloc

template<int F, int LOGF, bool RELU>
__global__ __launch_bounds__(512) void bucket_gather(const int* __restrict__ pairs,
        const int* __restrict__ scanG, int B, int NB,
        const float* __restrict__ g, const float* __restrict__ dis,
        const float* __restrict__ bias, float* __restrict__ out, int n, int E) {
    __shared__ float agg[BKT_NODES * F];
    int tid = threadIdx.x;
    int bkt = blockIdx.x;
    for (int i = tid; i < BKT_NODES * F; i += 512) agg[i] = 0.f;
    int e0 = scanG[(size_t)bkt * B];
    int e1 = (bkt + 1 < NB) ? scanG[(size_t)(bkt + 1) * B] : E;
    __syncthreads();

    int lane = tid & 63, wv = tid >> 6;
    int f = lane & (F - 1);
    const int EPW = 64 >> LOGF;       // edges per wave per step
    const int STRIDE = 8 * EPW;       // 8 waves
    int h = lane >> LOGF;
    int e = e0 + wv * EPW + h;
    // 2x unrolled for memory-level parallelism
    for (; e + STRIDE < e1; e += 2 * STRIDE) {
        int k1 = pairs[e];
        int k2 = pairs[e + STRIDE];
        float v1 = g[(size_t)(k1 >> BKT_SHIFT) * F + f];
        float v2 = g[(size_t)(k2 >> BKT_SHIFT) * F + f];
        atomicAdd(&agg[(k1 & (BKT_NODES - 1)) * F + f], v1);
        atomicAdd(&agg[(k2 & (BKT_NODES - 1)) * F + f], v2);
    }
    if (e < e1) {
        int k1 = pairs[e];
        atomicAdd(&agg[(k1 & (BKT_NODES - 1)) * F + f],
                  g[(size_t)(k1 >> BKT_SHIFT) * F + f]);
    }
    __syncthreads();

    int nb0 = bkt << BKT_SHIFT;
    for (int i = tid; i < BKT_NODES * F; i += 512) {
        int v = nb0 + (i >> LOGF);
        int f2 = i & (F - 1);
        if (v < n) {
            float dv = dis[v];
            float val = (agg[i] + g[(size_t)v * F + f2]) * dv + bias[f2];
            if (RELU) val = fmaxf(val, 0.f);
            out[(size_t)v * F + f2] = val;
        }
    }
}

// layer 3: gather (F=16 padded) + fused self-loop/bias + log_softmax (11 classes)
__global__ __launch_bounds__(512) void bucket_gather_sm(const int* __restrict__ pairs,
        const int* __restrict__ scanG, int B, int NB,
        const float* __restrict__ g, const float* __restrict__ dis,
        const float* __restrict__ bias, float* __restrict__ out, int n, int E) {
    __shared__ float agg[BKT_NODES * 16];
    int tid = threadIdx.x;
    int bkt = blockIdx.x;
    for (int i = tid; i < BKT_NODES * 16; i += 512) agg[i] = 0.f;
    int e0 = scanG[(size_t)bkt * B];
    int e1 = (bkt + 1 < NB) ? scanG[(size_t)(bkt + 1) * B] : E;
    __syncthreads();

    int lane = tid & 63, wv = tid >> 6;
    int f = lane & 15;
    const int EPW = 4;
    const int STRIDE = 32;
    int h = lane >> 4;
    int e = e0 + wv * EPW + h;
    for (; e + STRIDE < e1; e += 2 * STRIDE) {
        int k1 = pairs[e];
        int k2 = pairs[e + STRIDE];
        float v1 = g[(size_t)(k1 >> BKT_SHIFT) * 16 + f];
        float v2 = g[(size_t)(k2 >> BKT_SHIFT) * 16 + f];
        atomicAdd(&agg[(k1 & (BKT_NODES - 1)) * 16 + f], v1);
        atomicAdd(&agg[(k2 & (BKT_NODES - 1)) * 16 + f], v2);
    }
    if (e < e1) {
        int k1 = pairs[e];
        atomicAdd(&agg[(k1 & (BKT_NODES - 1)) * 16 + f],
                  g[(size_t)(k1 >> BKT_SHIFT) * 16 + f]);
    }
    __syncthreads();

    int nb0 = bkt << BKT_SHIFT;
    int sub = lane >> 4;  // 4 nodes per wave concurrently
    #pragma unroll
    for (int pass = 0; pass < 4; ++pass) {
        int dl = pass * 32 + wv * 4 + sub;
        int v = nb0 + dl;
        if (v < n) {
            float dv = dis[v];
            float val = (agg[dl * 16 + f] + g[(size_t)v * 16 + f]) * dv + ((f < 11) ? bias[f] : 0.f);
            float vm = (f < 11) ? val : -3.0e38f;
            #pragma unroll
            for (int m = 1; m < 16; m <<= 1) vm = fmaxf(vm, __shfl_xor(vm, m));
            float ex = (f < 11) ? __expf(val - vm) : 0.f;
            float sum = ex;
            #pragma unroll
            for (int m = 1; m < 16; m <<= 1) sum += __shfl_xor(sum, m);
            if (f < 11) out[(size_t)v * 11 + f] = val - (__logf(sum) + vm);
        }
    }
}

// ==================== launch ====================

extern "C" void kernel_launch(void* const* d_in, const int* in_sizes, int n_in,
                              void* d_out, int out_size, void* d_ws, size_t ws_size,
                              hipStream_t stream) {
    const float* x  = (const float*)d_in[0];
    const int*   ei = (const int*)d_in[1];
    const float* W1 = (const float*)d_in[2];
    const float* b1 = (const float*)d_in[3];
    const float* W2 = (const float*)d_in[4];
    const float* b2 = (const float*)d_in[5];
    const float* W3 = (const float*)d_in[6];
    const float* b3 = (const float*)d_in[7];
    float* out = (float*)d_out;

    const int n = in_sizes[0] / 512;
    const int E = in_sizes[1] / 2;
    const int* src = ei;
    const int* dst = ei + E;

    const int NB = (n + BKT_NODES - 1) >> BKT_SHIFT;      // buckets (782)
    const int B  = (E + CHUNK - 1) / CHUNK;               // hist/scatter blocks (196)
    const int NBB = NB * B;                               // flattened histogram size
    const int nb_scan = (NBB + SCAN_ELEMS - 1) / SCAN_ELEMS;

    // workspace layout (4B elements)
    int* ws0 = (int*)d_ws;
    size_t off = 0;
    int*   cnt    = ws0 + off; off += (size_t)n;
    float* dis    = (float*)(ws0 + off); off += (size_t)n;
    int*   scanG  = ws0 + off; off += (size_t)NBB;
    int*   blksum = ws0 + off; off += 256;
    int*   pairs  = ws0 + off; off += (size_t)E;
    float* gbuf   = (float*)(ws0 + off); off += (size_t)n * 32;
    float* hbuf   = (float*)(ws0 + off); off += (size_t)n * 32;
    int*   histG  = (int*)hbuf;  // alias: histG dead before hbuf first written

    // ---- degrees ----
    hipMemsetAsync(cnt, 0, (size_t)n * 4, stream);
    count_deg<<<(E + 255) / 256, 256, 0, stream>>>(dst, cnt, E);
    deg_to_dis<<<(n + 255) / 256, 256, 0, stream>>>(cnt, dis, n);

    // ---- bucket binning ----
    hist_k<<<B, 512, 0, stream>>>(dst, histG, B, NB, E);
    scan1<<<nb_scan, 256, 0, stream>>>(histG, scanG, blksum, NBB);
    scan2<<<1, 256, 0, stream>>>(blksum, nb_scan);
    scan3<<<(NBB + 255) / 256, 256, 0, stream>>>(scanG, blksum, NBB);
    scatter_k<<<B, 512, 0, stream>>>(src, dst, scanG, pairs, B, NB, E);

    // ---- layer 1 ----
    gemm1<<<(n + 127) / 128, 128, 0, stream>>>(x, W1, dis, gbuf, n);
    bucket_gather<32, 5, true><<<NB, 512, 0, stream>>>(pairs, scanG, B, NB, gbuf, dis, b1, hbuf, n, E);

    // ---- layer 2 ----
    gemm2<<<(n + 127) / 128, 128, 0, stream>>>(hbuf, W2, dis, gbuf, n);
    bucket_gather<16, 4, true><<<NB, 512, 0, stream>>>(pairs, scanG, B, NB, gbuf, dis, b2, hbuf, n, E);

    // ---- layer 3 ----
    gemm3<<<(n + 127) / 128, 128, 0, stream>>>(hbuf, W3, dis, gbuf, n);
    bucket_gather_sm<<<NB, 512, 0, stream>>>(pairs, scanG, B, NB, gbuf, dis, b3, out, n, E);
}

// Round 6
// 565.242 us; speedup vs baseline: 2.9159x; 2.9159x over previous
//
#include <hip/hip_runtime.h>

// ==================== degree ====================

__global__ void count_deg(const int* __restrict__ dst, int* __restrict__ cnt, int E) {
    int e = blockIdx.x * blockDim.x + threadIdx.x;
    if (e < E) atomicAdd(&cnt[dst[e]], 1);
}

__global__ void deg_to_dis(const int* __restrict__ cnt, float* __restrict__ dis, int n) {
    int i = blockIdx.x * blockDim.x + threadIdx.x;
    if (i < n) dis[i] = rsqrtf((float)cnt[i] + 1.0f);
}

// ==================== bucket binning ====================
#define BKT_SHIFT 7
#define BKT_NODES 128
#define CHUNK 16384  // edges per hist/scatter block (512 thr x 32)

__global__ __launch_bounds__(512) void hist_k(const int* __restrict__ dst, int* __restrict__ histG,
                                              int B, int NB, int E) {
    __shared__ int hist[1024];
    int tid = threadIdx.x;
    for (int i = tid; i < NB; i += 512) hist[i] = 0;
    __syncthreads();
    int base = blockIdx.x * CHUNK;
    for (int i = tid; i < CHUNK; i += 512) {
        int e = base + i;
        if (e >= E) break;
        atomicAdd(&hist[dst[e] >> BKT_SHIFT], 1);
    }
    __syncthreads();
    for (int i = tid; i < NB; i += 512) histG[(size_t)i * B + blockIdx.x] = hist[i];
}

__global__ __launch_bounds__(512) void scatter_k(const int* __restrict__ src, const int* __restrict__ dst,
                                                 const int* __restrict__ scanG, int* __restrict__ pairs,
                                                 int B, int NB, int E) {
    __shared__ int sbase[1024];
    __shared__ int scnt[1024];
    int tid = threadIdx.x;
    for (int i = tid; i < NB; i += 512) {
        sbase[i] = scanG[(size_t)i * B + blockIdx.x];
        scnt[i] = 0;
    }
    __syncthreads();
    int base = blockIdx.x * CHUNK;
    for (int i = tid; i < CHUNK; i += 512) {
        int e = base + i;
        if (e >= E) break;
        int d = dst[e], s = src[e];
        int b = d >> BKT_SHIFT;
        int r = atomicAdd(&scnt[b], 1);
        pairs[sbase[b] + r] = (s << BKT_SHIFT) | (d & (BKT_NODES - 1));
    }
}

// ==================== scan (exclusive), 256 thr x 8 = 2048 elems/block ====================
#define SCAN_VPT 8
#define SCAN_ELEMS 2048

__global__ __launch_bounds__(256) void scan1(const int* __restrict__ in, int* __restrict__ out,
                                             int* __restrict__ blksum, int n) {
    __shared__ int sh[256];
    int base = blockIdx.x * SCAN_ELEMS + threadIdx.x * SCAN_VPT;
    int v[SCAN_VPT];
    int sum = 0;
    #pragma unroll
    for (int j = 0; j < SCAN_VPT; ++j) {
        v[j] = (base + j < n) ? in[base + j] : 0;
        sum += v[j];
    }
    sh[threadIdx.x] = sum;
    __syncthreads();
    for (int off = 1; off < 256; off <<= 1) {
        int t = (threadIdx.x >= off) ? sh[threadIdx.x - off] : 0;
        __syncthreads();
        sh[threadIdx.x] += t;
        __syncthreads();
    }
    if (threadIdx.x == 255) blksum[blockIdx.x] = sh[255];
    int run = sh[threadIdx.x] - sum;
    #pragma unroll
    for (int j = 0; j < SCAN_VPT; ++j) {
        if (base + j < n) out[base + j] = run;
        run += v[j];
    }
}

__global__ __launch_bounds__(256) void scan2(int* __restrict__ blksum, int nb) {
    __shared__ int sh[256];
    int t = threadIdx.x;
    int v = (t < nb) ? blksum[t] : 0;
    sh[t] = v;
    __syncthreads();
    for (int off = 1; off < 256; off <<= 1) {
        int u = (t >= off) ? sh[t - off] : 0;
        __syncthreads();
        sh[t] += u;
        __syncthreads();
    }
    if (t < nb) blksum[t] = sh[t] - v;
}

__global__ void scan3(int* __restrict__ out, const int* __restrict__ blksum, int n) {
    int i = blockIdx.x * blockDim.x + threadIdx.x;
    if (i < n) out[i] += blksum[i >> 11];
}

// ==================== within-bucket counting sort -> dst-sorted CSR ====================
#define SORT_CAP 8192  // mean bucket size 4096, std 64 -> 8192 is unreachable

__global__ __launch_bounds__(256) void sort_bucket(const int* __restrict__ pairs,
        const int* __restrict__ scanG, int B, int NB,
        int* __restrict__ csr_src, int* __restrict__ node_start, int n, int E) {
    __shared__ int keys[SORT_CAP];
    __shared__ int lcnt[BKT_NODES];
    __shared__ int lscan[BKT_NODES];
    __shared__ int lfill[BKT_NODES];
    int bkt = blockIdx.x, tid = threadIdx.x;
    int e0 = scanG[(size_t)bkt * B];
    int e1 = (bkt + 1 < NB) ? scanG[(size_t)(bkt + 1) * B] : E;
    int m = e1 - e0;
    if (tid < BKT_NODES) { lcnt[tid] = 0; lfill[tid] = 0; }
    __syncthreads();
    for (int i = tid; i < m; i += 256) {
        int k = pairs[e0 + i];
        if (i < SORT_CAP) keys[i] = k;
        atomicAdd(&lcnt[k & (BKT_NODES - 1)], 1);
    }
    __syncthreads();
    if (tid == 0) {
        int run = 0;
        for (int i = 0; i < BKT_NODES; ++i) { lscan[i] = run; run += lcnt[i]; }
    }
    __syncthreads();
    int nb0 = bkt << BKT_SHIFT;
    if (tid < BKT_NODES && nb0 + tid < n) node_start[nb0 + tid] = e0 + lscan[tid];
    for (int i = tid; i < m; i += 256) {
        int k = (i < SORT_CAP) ? keys[i] : pairs[e0 + i];
        int d = k & (BKT_NODES - 1);
        int pos = lscan[d] + atomicAdd(&lfill[d], 1);
        csr_src[e0 + pos] = k >> BKT_SHIFT;
    }
}

// ==================== GEMMs (epilogue scales row by dis[node] -> g) ====================

__global__ __launch_bounds__(128) void gemm1(const float* __restrict__ x, const float* __restrict__ W,
                                             const float* __restrict__ dis, float* __restrict__ g, int n) {
    __shared__ float ws[32 * 32];
    __shared__ float xs[128][33];
    int tid = threadIdx.x;
    int node0 = blockIdx.x * 128;
    int node = node0 + tid;
    float acc[32];
    #pragma unroll
    for (int c = 0; c < 32; ++c) acc[c] = 0.f;

    for (int k0 = 0; k0 < 512; k0 += 32) {
        __syncthreads();
        #pragma unroll
        for (int r = 0; r < 2; ++r) {
            int fi = tid + r * 128;
            int k = fi >> 3, c4 = fi & 7;
            float4 wv = *(const float4*)(W + (size_t)(k0 + k) * 32 + c4 * 4);
            *((float4*)(ws + k * 32 + c4 * 4)) = wv;
        }
        #pragma unroll
        for (int r = 0; r < 8; ++r) {
            int fi = tid + r * 128;
            int nd = fi >> 3, k4 = fi & 7;
            int gn = min(node0 + nd, n - 1);
            float4 xv = *(const float4*)(x + (size_t)gn * 512 + k0 + k4 * 4);
            xs[nd][k4 * 4 + 0] = xv.x;
            xs[nd][k4 * 4 + 1] = xv.y;
            xs[nd][k4 * 4 + 2] = xv.z;
            xs[nd][k4 * 4 + 3] = xv.w;
        }
        __syncthreads();
        #pragma unroll
        for (int k = 0; k < 32; ++k) {
            float xv = xs[tid][k];
            #pragma unroll
            for (int c = 0; c < 32; ++c) acc[c] += xv * ws[k * 32 + c];
        }
    }
    if (node < n) {
        float dv = dis[node];
        float4* out4 = (float4*)(g + (size_t)node * 32);
        #pragma unroll
        for (int c4 = 0; c4 < 8; ++c4)
            out4[c4] = make_float4(acc[c4 * 4] * dv, acc[c4 * 4 + 1] * dv,
                                   acc[c4 * 4 + 2] * dv, acc[c4 * 4 + 3] * dv);
    }
}

__global__ __launch_bounds__(128) void gemm2(const float* __restrict__ xin, const float* __restrict__ W,
                                             const float* __restrict__ dis, float* __restrict__ g, int n) {
    __shared__ float ws[32 * 16];
    __shared__ float xs[128][33];
    int tid = threadIdx.x;
    int node0 = blockIdx.x * 128;
    int node = node0 + tid;
    {
        int k = tid >> 2, c4 = tid & 3;
        float4 wv = *(const float4*)(W + (size_t)k * 16 + c4 * 4);
        *((float4*)(ws + k * 16 + c4 * 4)) = wv;
    }
    #pragma unroll
    for (int r = 0; r < 8; ++r) {
        int fi = tid + r * 128;
        int nd = fi >> 3, k4 = fi & 7;
        int gn = min(node0 + nd, n - 1);
        float4 xv = *(const float4*)(xin + (size_t)gn * 32 + k4 * 4);
        xs[nd][k4 * 4 + 0] = xv.x;
        xs[nd][k4 * 4 + 1] = xv.y;
        xs[nd][k4 * 4 + 2] = xv.z;
        xs[nd][k4 * 4 + 3] = xv.w;
    }
    __syncthreads();
    float acc[16];
    #pragma unroll
    for (int c = 0; c < 16; ++c) acc[c] = 0.f;
    #pragma unroll
    for (int k = 0; k < 32; ++k) {
        float xv = xs[tid][k];
        #pragma unroll
        for (int c = 0; c < 16; ++c) acc[c] += xv * ws[k * 16 + c];
    }
    if (node < n) {
        float dv = dis[node];
        float4* out4 = (float4*)(g + (size_t)node * 16);
        #pragma unroll
        for (int c4 = 0; c4 < 4; ++c4)
            out4[c4] = make_float4(acc[c4 * 4] * dv, acc[c4 * 4 + 1] * dv,
                                   acc[c4 * 4 + 2] * dv, acc[c4 * 4 + 3] * dv);
    }
}

__global__ __launch_bounds__(128) void gemm3(const float* __restrict__ xin, const float* __restrict__ W,
                                             const float* __restrict__ dis, float* __restrict__ g, int n) {
    __shared__ float ws[16 * 16];
    __shared__ float xs[128][17];
    int tid = threadIdx.x;
    int node0 = blockIdx.x * 128;
    int node = node0 + tid;
    #pragma unroll
    for (int fi = 0; fi < 2; ++fi) {
        int i = tid + fi * 128;
        int k = i >> 4, c = i & 15;
        ws[i] = (c < 11) ? W[(size_t)k * 11 + c] : 0.f;
    }
    #pragma unroll
    for (int r = 0; r < 4; ++r) {
        int fi = tid + r * 128;
        int nd = fi >> 2, k4 = fi & 3;
        int gn = min(node0 + nd, n - 1);
        float4 xv = *(const float4*)(xin + (size_t)gn * 16 + k4 * 4);
        xs[nd][k4 * 4 + 0] = xv.x;
        xs[nd][k4 * 4 + 1] = xv.y;
        xs[nd][k4 * 4 + 2] = xv.z;
        xs[nd][k4 * 4 + 3] = xv.w;
    }
    __syncthreads();
    float acc[16];
    #pragma unroll
    for (int c = 0; c < 16; ++c) acc[c] = 0.f;
    #pragma unroll
    for (int k = 0; k < 16; ++k) {
        float xv = xs[tid][k];
        #pragma unroll
        for (int c = 0; c < 16; ++c) acc[c] += xv * ws[k * 16 + c];
    }
    if (node < n) {
        float dv = dis[node];
        float4* out4 = (float4*)(g + (size_t)node * 16);
        #pragma unroll
        for (int c4 = 0; c4 < 4; ++c4)
            out4[c4] = make_float4(acc[c4 * 4] * dv, acc[c4 * 4 + 1] * dv,
                                   acc[c4 * 4 + 2] * dv, acc[c4 * 4 + 3] * dv);
    }
}

// ==================== node-parallel CSR gather (one wave per node) ====================
// out[v] = relu?((sum_{e in CSR(v)} g[src] + g[v]) * dis[v] + b)

template<int F, int LOGF, bool RELU>
__global__ __launch_bounds__(256) void gather_csr(const int* __restrict__ csr_src,
        const int* __restrict__ start, const int* __restrict__ cnt,
        const float* __restrict__ g, const float* __restrict__ dis,
        const float* __restrict__ bias, float* __restrict__ out, int n) {
    int node = blockIdx.x * 4 + (threadIdx.x >> 6);
    if (node >= n) return;
    int lane = threadIdx.x & 63;
    int f = lane & (F - 1);
    int j = lane >> LOGF;
    const int EPI = 64 / F;
    int i0 = start[node], i1 = i0 + cnt[node];
    float acc = 0.f;
    int i = i0 + j;
    // 2x independent-chain unroll for MLP
    for (; i + EPI < i1; i += 2 * EPI) {
        int s1 = csr_src[i];
        int s2 = csr_src[i + EPI];
        acc += g[(size_t)s1 * F + f];
        acc += g[(size_t)s2 * F + f];
    }
    if (i < i1) acc += g[(size_t)csr_src[i] * F + f];
    #pragma unroll
    for (int m = F; m < 64; m <<= 1) acc += __shfl_xor(acc, m);
    float val = (acc + g[(size_t)node * F + f]) * dis[node] + bias[f];
    if (RELU) val = fmaxf(val, 0.f);
    if (lane < F) out[(size_t)node * F + f] = val;
}

// layer 3 gather + fused log_softmax (stride 16 in, 11 classes out)
__global__ __launch_bounds__(256) void gather3(const int* __restrict__ csr_src,
        const int* __restrict__ start, const int* __restrict__ cnt,
        const float* __restrict__ g, const float* __restrict__ dis,
        const float* __restrict__ bias, float* __restrict__ out, int n) {
    int node = blockIdx.x * 4 + (threadIdx.x >> 6);
    if (node >= n) return;
    int lane = threadIdx.x & 63;
    int f = lane & 15;
    int j = lane >> 4;
    int i0 = start[node], i1 = i0 + cnt[node];
    float acc = 0.f;
    int i = i0 + j;
    for (; i + 4 < i1; i += 8) {
        int s1 = csr_src[i];
        int s2 = csr_src[i + 4];
        acc += g[(size_t)s1 * 16 + f];
        acc += g[(size_t)s2 * 16 + f];
    }
    if (i < i1) acc += g[(size_t)csr_src[i] * 16 + f];
    acc += __shfl_xor(acc, 16);
    acc += __shfl_xor(acc, 32);
    float val = (acc + g[(size_t)node * 16 + f]) * dis[node] + ((f < 11) ? bias[f] : 0.f);
    float vm = (f < 11) ? val : -3.0e38f;
    #pragma unroll
    for (int m = 1; m < 16; m <<= 1) vm = fmaxf(vm, __shfl_xor(vm, m));
    float ex = (f < 11) ? __expf(val - vm) : 0.f;
    float sum = ex;
    #pragma unroll
    for (int m = 1; m < 16; m <<= 1) sum += __shfl_xor(sum, m);
    if (lane < 11) out[(size_t)node * 11 + f] = val - (__logf(sum) + vm);
}

// ==================== launch ====================

extern "C" void kernel_launch(void* const* d_in, const int* in_sizes, int n_in,
                              void* d_out, int out_size, void* d_ws, size_t ws_size,
                              hipStream_t stream) {
    const float* x  = (const float*)d_in[0];
    const int*   ei = (const int*)d_in[1];
    const float* W1 = (const float*)d_in[2];
    const float* b1 = (const float*)d_in[3];
    const float* W2 = (const float*)d_in[4];
    const float* b2 = (const float*)d_in[5];
    const float* W3 = (const float*)d_in[6];
    const float* b3 = (const float*)d_in[7];
    float* out = (float*)d_out;

    const int n = in_sizes[0] / 512;
    const int E = in_sizes[1] / 2;
    const int* src = ei;
    const int* dst = ei + E;

    const int NB = (n + BKT_NODES - 1) >> BKT_SHIFT;      // buckets (782)
    const int B  = (E + CHUNK - 1) / CHUNK;               // hist/scatter blocks (196)
    const int NBB = NB * B;                               // flattened histogram
    const int nb_scan = (NBB + SCAN_ELEMS - 1) / SCAN_ELEMS;

    // workspace layout (4B elements)
    int* ws0 = (int*)d_ws;
    size_t off = 0;
    int*   cnt     = ws0 + off; off += (size_t)n;
    float* dis     = (float*)(ws0 + off); off += (size_t)n;
    int*   nstart  = ws0 + off; off += (size_t)n;
    int*   scanG   = ws0 + off; off += (size_t)NBB;
    int*   blksum  = ws0 + off; off += 256;
    int*   pairs   = ws0 + off; off += (size_t)E;
    int*   csr_src = ws0 + off; off += (size_t)E;
    float* gbuf    = (float*)(ws0 + off); off += (size_t)n * 32;
    float* hbuf    = (float*)(ws0 + off); off += (size_t)n * 32;
    int*   histG   = (int*)hbuf;  // alias: histG dead before hbuf first written

    // ---- degrees ----
    hipMemsetAsync(cnt, 0, (size_t)n * 4, stream);
    count_deg<<<(E + 255) / 256, 256, 0, stream>>>(dst, cnt, E);
    deg_to_dis<<<(n + 255) / 256, 256, 0, stream>>>(cnt, dis, n);

    // ---- bucket binning + within-bucket counting sort -> dst-sorted CSR ----
    hist_k<<<B, 512, 0, stream>>>(dst, histG, B, NB, E);
    scan1<<<nb_scan, 256, 0, stream>>>(histG, scanG, blksum, NBB);
    scan2<<<1, 256, 0, stream>>>(blksum, nb_scan);
    scan3<<<(NBB + 255) / 256, 256, 0, stream>>>(scanG, blksum, NBB);
    scatter_k<<<B, 512, 0, stream>>>(src, dst, scanG, pairs, B, NB, E);
    sort_bucket<<<NB, 256, 0, stream>>>(pairs, scanG, B, NB, csr_src, nstart, n, E);

    // ---- layer 1 ----
    gemm1<<<(n + 127) / 128, 128, 0, stream>>>(x, W1, dis, gbuf, n);
    gather_csr<32, 5, true><<<(n + 3) / 4, 256, 0, stream>>>(csr_src, nstart, cnt, gbuf, dis, b1, hbuf, n);

    // ---- layer 2 ----
    gemm2<<<(n + 127) / 128, 128, 0, stream>>>(hbuf, W2, dis, gbuf, n);
    gather_csr<16, 4, true><<<(n + 3) / 4, 256, 0, stream>>>(csr_src, nstart, cnt, gbuf, dis, b2, hbuf, n);

    // ---- layer 3 ----
    gemm3<<<(n + 127) / 128, 128, 0, stream>>>(hbuf, W3, dis, gbuf, n);
    gather3<<<(n + 3) / 4, 256, 0, stream>>>(csr_src, nstart, cnt, gbuf, dis, b3, out, n);
}

// Round 7
// 408.687 us; speedup vs baseline: 4.0329x; 1.3831x over previous
//
#include <hip/hip_runtime.h>

// ==================== bucket binning ====================
#define BKT_SHIFT 7
#define BKT_NODES 128
#define CHUNK 16384  // edges per hist/scatter block (512 thr x 32)

__global__ __launch_bounds__(512) void hist_k(const int* __restrict__ dst, int* __restrict__ histG,
                                              int B, int NB, int E) {
    __shared__ int hist[1024];
    int tid = threadIdx.x;
    for (int i = tid; i < NB; i += 512) hist[i] = 0;
    __syncthreads();
    int base = blockIdx.x * CHUNK;
    for (int i = tid; i < CHUNK; i += 512) {
        int e = base + i;
        if (e >= E) break;
        atomicAdd(&hist[dst[e] >> BKT_SHIFT], 1);
    }
    __syncthreads();
    for (int i = tid; i < NB; i += 512) histG[(size_t)i * B + blockIdx.x] = hist[i];
}

__global__ __launch_bounds__(512) void scatter_k(const int* __restrict__ src, const int* __restrict__ dst,
                                                 const int* __restrict__ scanG, int* __restrict__ pairs,
                                                 int B, int NB, int E) {
    __shared__ int sbase[1024];
    __shared__ int scnt[1024];
    int tid = threadIdx.x;
    for (int i = tid; i < NB; i += 512) {
        sbase[i] = scanG[(size_t)i * B + blockIdx.x];
        scnt[i] = 0;
    }
    __syncthreads();
    int base = blockIdx.x * CHUNK;
    for (int i = tid; i < CHUNK; i += 512) {
        int e = base + i;
        if (e >= E) break;
        int d = dst[e], s = src[e];
        int b = d >> BKT_SHIFT;
        int r = atomicAdd(&scnt[b], 1);
        pairs[sbase[b] + r] = (s << BKT_SHIFT) | (d & (BKT_NODES - 1));
    }
}

// ==================== scan (exclusive), 256 thr x 8 = 2048 elems/block ====================
#define SCAN_VPT 8
#define SCAN_ELEMS 2048

__global__ __launch_bounds__(256) void scan1(const int* __restrict__ in, int* __restrict__ out,
                                             int* __restrict__ blksum, int n) {
    __shared__ int sh[256];
    int base = blockIdx.x * SCAN_ELEMS + threadIdx.x * SCAN_VPT;
    int v[SCAN_VPT];
    int sum = 0;
    #pragma unroll
    for (int j = 0; j < SCAN_VPT; ++j) {
        v[j] = (base + j < n) ? in[base + j] : 0;
        sum += v[j];
    }
    sh[threadIdx.x] = sum;
    __syncthreads();
    for (int off = 1; off < 256; off <<= 1) {
        int t = (threadIdx.x >= off) ? sh[threadIdx.x - off] : 0;
        __syncthreads();
        sh[threadIdx.x] += t;
        __syncthreads();
    }
    if (threadIdx.x == 255) blksum[blockIdx.x] = sh[255];
    int run = sh[threadIdx.x] - sum;
    #pragma unroll
    for (int j = 0; j < SCAN_VPT; ++j) {
        if (base + j < n) out[base + j] = run;
        run += v[j];
    }
}

__global__ __launch_bounds__(256) void scan2(int* __restrict__ blksum, int nb) {
    __shared__ int sh[256];
    int t = threadIdx.x;
    int v = (t < nb) ? blksum[t] : 0;
    sh[t] = v;
    __syncthreads();
    for (int off = 1; off < 256; off <<= 1) {
        int u = (t >= off) ? sh[t - off] : 0;
        __syncthreads();
        sh[t] += u;
        __syncthreads();
    }
    if (t < nb) blksum[t] = sh[t] - v;
}

__global__ void scan3(int* __restrict__ out, const int* __restrict__ blksum, int n) {
    int i = blockIdx.x * blockDim.x + threadIdx.x;
    if (i < n) out[i] += blksum[i >> 11];
}

// ==================== within-bucket counting sort -> dst-sorted CSR + degree/dis ====================
#define SORT_CAP 8192  // mean bucket size 4096, std 64 -> 8192 is unreachable

__global__ __launch_bounds__(256) void sort_bucket(const int* __restrict__ pairs,
        const int* __restrict__ scanG, int B, int NB,
        int* __restrict__ csr_src, int* __restrict__ node_start,
        int* __restrict__ cnt, float* __restrict__ dis, int n, int E) {
    __shared__ int keys[SORT_CAP];
    __shared__ int lcnt[BKT_NODES];
    __shared__ int lscan[BKT_NODES];
    __shared__ int lfill[BKT_NODES];
    int bkt = blockIdx.x, tid = threadIdx.x;
    int e0 = scanG[(size_t)bkt * B];
    int e1 = (bkt + 1 < NB) ? scanG[(size_t)(bkt + 1) * B] : E;
    int m = e1 - e0;
    if (tid < BKT_NODES) { lcnt[tid] = 0; lfill[tid] = 0; }
    __syncthreads();
    for (int i = tid; i < m; i += 256) {
        int k = pairs[e0 + i];
        if (i < SORT_CAP) keys[i] = k;
        atomicAdd(&lcnt[k & (BKT_NODES - 1)], 1);
    }
    __syncthreads();
    if (tid == 0) {
        int run = 0;
        for (int i = 0; i < BKT_NODES; ++i) { lscan[i] = run; run += lcnt[i]; }
    }
    __syncthreads();
    int nb0 = bkt << BKT_SHIFT;
    if (tid < BKT_NODES && nb0 + tid < n) {
        int deg = lcnt[tid];
        node_start[nb0 + tid] = e0 + lscan[tid];
        cnt[nb0 + tid] = deg;
        dis[nb0 + tid] = rsqrtf((float)deg + 1.0f);
    }
    for (int i = tid; i < m; i += 256) {
        int k = (i < SORT_CAP) ? keys[i] : pairs[e0 + i];
        int d = k & (BKT_NODES - 1);
        int pos = lscan[d] + atomicAdd(&lfill[d], 1);
        csr_src[e0 + pos] = k >> BKT_SHIFT;
    }
}

// ==================== GEMMs (epilogue scales row by dis[node] -> g) ====================

__global__ __launch_bounds__(128) void gemm1(const float* __restrict__ x, const float* __restrict__ W,
                                             const float* __restrict__ dis, float* __restrict__ g, int n) {
    __shared__ float ws[32 * 32];
    __shared__ float xs[128][33];
    int tid = threadIdx.x;
    int node0 = blockIdx.x * 128;
    int node = node0 + tid;
    float acc[32];
    #pragma unroll
    for (int c = 0; c < 32; ++c) acc[c] = 0.f;

    for (int k0 = 0; k0 < 512; k0 += 32) {
        __syncthreads();
        #pragma unroll
        for (int r = 0; r < 2; ++r) {
            int fi = tid + r * 128;
            int k = fi >> 3, c4 = fi & 7;
            float4 wv = *(const float4*)(W + (size_t)(k0 + k) * 32 + c4 * 4);
            *((float4*)(ws + k * 32 + c4 * 4)) = wv;
        }
        #pragma unroll
        for (int r = 0; r < 8; ++r) {
            int fi = tid + r * 128;
            int nd = fi >> 3, k4 = fi & 7;
            int gn = min(node0 + nd, n - 1);
            float4 xv = *(const float4*)(x + (size_t)gn * 512 + k0 + k4 * 4);
            xs[nd][k4 * 4 + 0] = xv.x;
            xs[nd][k4 * 4 + 1] = xv.y;
            xs[nd][k4 * 4 + 2] = xv.z;
            xs[nd][k4 * 4 + 3] = xv.w;
        }
        __syncthreads();
        #pragma unroll
        for (int k = 0; k < 32; ++k) {
            float xv = xs[tid][k];
            #pragma unroll
            for (int c = 0; c < 32; ++c) acc[c] += xv * ws[k * 32 + c];
        }
    }
    if (node < n) {
        float dv = dis[node];
        float4* out4 = (float4*)(g + (size_t)node * 32);
        #pragma unroll
        for (int c4 = 0; c4 < 8; ++c4)
            out4[c4] = make_float4(acc[c4 * 4] * dv, acc[c4 * 4 + 1] * dv,
                                   acc[c4 * 4 + 2] * dv, acc[c4 * 4 + 3] * dv);
    }
}

__global__ __launch_bounds__(128) void gemm2(const float* __restrict__ xin, const float* __restrict__ W,
                                             const float* __restrict__ dis, float* __restrict__ g, int n) {
    __shared__ float ws[32 * 16];
    __shared__ float xs[128][33];
    int tid = threadIdx.x;
    int node0 = blockIdx.x * 128;
    int node = node0 + tid;
    {
        int k = tid >> 2, c4 = tid & 3;
        float4 wv = *(const float4*)(W + (size_t)k * 16 + c4 * 4);
        *((float4*)(ws + k * 16 + c4 * 4)) = wv;
    }
    #pragma unroll
    for (int r = 0; r < 8; ++r) {
        int fi = tid + r * 128;
        int nd = fi >> 3, k4 = fi & 7;
        int gn = min(node0 + nd, n - 1);
        float4 xv = *(const float4*)(xin + (size_t)gn * 32 + k4 * 4);
        xs[nd][k4 * 4 + 0] = xv.x;
        xs[nd][k4 * 4 + 1] = xv.y;
        xs[nd][k4 * 4 + 2] = xv.z;
        xs[nd][k4 * 4 + 3] = xv.w;
    }
    __syncthreads();
    float acc[16];
    #pragma unroll
    for (int c = 0; c < 16; ++c) acc[c] = 0.f;
    #pragma unroll
    for (int k = 0; k < 32; ++k) {
        float xv = xs[tid][k];
        #pragma unroll
        for (int c = 0; c < 16; ++c) acc[c] += xv * ws[k * 16 + c];
    }
    if (node < n) {
        float dv = dis[node];
        float4* out4 = (float4*)(g + (size_t)node * 16);
        #pragma unroll
        for (int c4 = 0; c4 < 4; ++c4)
            out4[c4] = make_float4(acc[c4 * 4] * dv, acc[c4 * 4 + 1] * dv,
                                   acc[c4 * 4 + 2] * dv, acc[c4 * 4 + 3] * dv);
    }
}

__global__ __launch_bounds__(128) void gemm3(const float* __restrict__ xin, const float* __restrict__ W,
                                             const float* __restrict__ dis, float* __restrict__ g, int n) {
    __shared__ float ws[16 * 16];
    __shared__ float xs[128][17];
    int tid = threadIdx.x;
    int node0 = blockIdx.x * 128;
    int node = node0 + tid;
    #pragma unroll
    for (int fi = 0; fi < 2; ++fi) {
        int i = tid + fi * 128;
        int k = i >> 4, c = i & 15;
        ws[i] = (c < 11) ? W[(size_t)k * 11 + c] : 0.f;
    }
    #pragma unroll
    for (int r = 0; r < 4; ++r) {
        int fi = tid + r * 128;
        int nd = fi >> 2, k4 = fi & 3;
        int gn = min(node0 + nd, n - 1);
        float4 xv = *(const float4*)(xin + (size_t)gn * 16 + k4 * 4);
        xs[nd][k4 * 4 + 0] = xv.x;
        xs[nd][k4 * 4 + 1] = xv.y;
        xs[nd][k4 * 4 + 2] = xv.z;
        xs[nd][k4 * 4 + 3] = xv.w;
    }
    __syncthreads();
    float acc[16];
    #pragma unroll
    for (int c = 0; c < 16; ++c) acc[c] = 0.f;
    #pragma unroll
    for (int k = 0; k < 16; ++k) {
        float xv = xs[tid][k];
        #pragma unroll
        for (int c = 0; c < 16; ++c) acc[c] += xv * ws[k * 16 + c];
    }
    if (node < n) {
        float dv = dis[node];
        float4* out4 = (float4*)(g + (size_t)node * 16);
        #pragma unroll
        for (int c4 = 0; c4 < 4; ++c4)
            out4[c4] = make_float4(acc[c4 * 4] * dv, acc[c4 * 4 + 1] * dv,
                                   acc[c4 * 4 + 2] * dv, acc[c4 * 4 + 3] * dv);
    }
}

// ==================== node-parallel CSR gather (one wave per node) ====================
// out[v] = relu?((sum_{e in CSR(v)} g[src] + g[v]) * dis[v] + b)

template<int F, int LOGF, bool RELU>
__global__ __launch_bounds__(256) void gather_csr(const int* __restrict__ csr_src,
        const int* __restrict__ start, const int* __restrict__ cnt,
        const float* __restrict__ g, const float* __restrict__ dis,
        const float* __restrict__ bias, float* __restrict__ out, int n) {
    int node = blockIdx.x * 4 + (threadIdx.x >> 6);
    if (node >= n) return;
    int lane = threadIdx.x & 63;
    int f = lane & (F - 1);
    int j = lane >> LOGF;
    const int EPI = 64 / F;
    int i0 = start[node], i1 = i0 + cnt[node];
    float acc = 0.f;
    int i = i0 + j;
    // 4x independent-chain unroll for MLP
    for (; i + 3 * EPI < i1; i += 4 * EPI) {
        int s1 = csr_src[i];
        int s2 = csr_src[i + EPI];
        int s3 = csr_src[i + 2 * EPI];
        int s4 = csr_src[i + 3 * EPI];
        float v1 = g[(size_t)s1 * F + f];
        float v2 = g[(size_t)s2 * F + f];
        float v3 = g[(size_t)s3 * F + f];
        float v4 = g[(size_t)s4 * F + f];
        acc += v1 + v2 + v3 + v4;
    }
    for (; i < i1; i += EPI) acc += g[(size_t)csr_src[i] * F + f];
    #pragma unroll
    for (int m = F; m < 64; m <<= 1) acc += __shfl_xor(acc, m);
    float val = (acc + g[(size_t)node * F + f]) * dis[node] + bias[f];
    if (RELU) val = fmaxf(val, 0.f);
    if (lane < F) out[(size_t)node * F + f] = val;
}

// layer 3 gather + fused log_softmax (stride 16 in, 11 classes out)
__global__ __launch_bounds__(256) void gather3(const int* __restrict__ csr_src,
        const int* __restrict__ start, const int* __restrict__ cnt,
        const float* __restrict__ g, const float* __restrict__ dis,
        const float* __restrict__ bias, float* __restrict__ out, int n) {
    int node = blockIdx.x * 4 + (threadIdx.x >> 6);
    if (node >= n) return;
    int lane = threadIdx.x & 63;
    int f = lane & 15;
    int j = lane >> 4;
    int i0 = start[node], i1 = i0 + cnt[node];
    float acc = 0.f;
    int i = i0 + j;
    for (; i + 12 < i1; i += 16) {
        int s1 = csr_src[i];
        int s2 = csr_src[i + 4];
        int s3 = csr_src[i + 8];
        int s4 = csr_src[i + 12];
        float v1 = g[(size_t)s1 * 16 + f];
        float v2 = g[(size_t)s2 * 16 + f];
        float v3 = g[(size_t)s3 * 16 + f];
        float v4 = g[(size_t)s4 * 16 + f];
        acc += v1 + v2 + v3 + v4;
    }
    for (; i < i1; i += 4) acc += g[(size_t)csr_src[i] * 16 + f];
    acc += __shfl_xor(acc, 16);
    acc += __shfl_xor(acc, 32);
    float val = (acc + g[(size_t)node * 16 + f]) * dis[node] + ((f < 11) ? bias[f] : 0.f);
    float vm = (f < 11) ? val : -3.0e38f;
    #pragma unroll
    for (int m = 1; m < 16; m <<= 1) vm = fmaxf(vm, __shfl_xor(vm, m));
    float ex = (f < 11) ? __expf(val - vm) : 0.f;
    float sum = ex;
    #pragma unroll
    for (int m = 1; m < 16; m <<= 1) sum += __shfl_xor(sum, m);
    if (lane < 11) out[(size_t)node * 11 + f] = val - (__logf(sum) + vm);
}

// ==================== launch ====================

extern "C" void kernel_launch(void* const* d_in, const int* in_sizes, int n_in,
                              void* d_out, int out_size, void* d_ws, size_t ws_size,
                              hipStream_t stream) {
    const float* x  = (const float*)d_in[0];
    const int*   ei = (const int*)d_in[1];
    const float* W1 = (const float*)d_in[2];
    const float* b1 = (const float*)d_in[3];
    const float* W2 = (const float*)d_in[4];
    const float* b2 = (const float*)d_in[5];
    const float* W3 = (const float*)d_in[6];
    const float* b3 = (const float*)d_in[7];
    float* out = (float*)d_out;

    const int n = in_sizes[0] / 512;
    const int E = in_sizes[1] / 2;
    const int* src = ei;
    const int* dst = ei + E;

    const int NB = (n + BKT_NODES - 1) >> BKT_SHIFT;      // buckets (782)
    const int B  = (E + CHUNK - 1) / CHUNK;               // hist/scatter blocks (196)
    const int NBB = NB * B;                               // flattened histogram
    const int nb_scan = (NBB + SCAN_ELEMS - 1) / SCAN_ELEMS;

    // workspace layout (4B elements)
    int* ws0 = (int*)d_ws;
    size_t off = 0;
    int*   cnt     = ws0 + off; off += (size_t)n;
    float* dis     = (float*)(ws0 + off); off += (size_t)n;
    int*   nstart  = ws0 + off; off += (size_t)n;
    int*   scanG   = ws0 + off; off += (size_t)NBB;
    int*   blksum  = ws0 + off; off += 256;
    int*   pairs   = ws0 + off; off += (size_t)E;
    int*   csr_src = ws0 + off; off += (size_t)E;
    float* gbuf    = (float*)(ws0 + off); off += (size_t)n * 32;
    float* hbuf    = (float*)(ws0 + off); off += (size_t)n * 32;
    int*   histG   = (int*)hbuf;  // alias: histG dead before hbuf first written

    // ---- bucket binning + within-bucket counting sort -> dst-sorted CSR + deg/dis ----
    hist_k<<<B, 512, 0, stream>>>(dst, histG, B, NB, E);
    scan1<<<nb_scan, 256, 0, stream>>>(histG, scanG, blksum, NBB);
    scan2<<<1, 256, 0, stream>>>(blksum, nb_scan);
    scan3<<<(NBB + 255) / 256, 256, 0, stream>>>(scanG, blksum, NBB);
    scatter_k<<<B, 512, 0, stream>>>(src, dst, scanG, pairs, B, NB, E);
    sort_bucket<<<NB, 256, 0, stream>>>(pairs, scanG, B, NB, csr_src, nstart, cnt, dis, n, E);

    // ---- layer 1 ----
    gemm1<<<(n + 127) / 128, 128, 0, stream>>>(x, W1, dis, gbuf, n);
    gather_csr<32, 5, true><<<(n + 3) / 4, 256, 0, stream>>>(csr_src, nstart, cnt, gbuf, dis, b1, hbuf, n);

    // ---- layer 2 ----
    gemm2<<<(n + 127) / 128, 128, 0, stream>>>(hbuf, W2, dis, gbuf, n);
    gather_csr<16, 4, true><<<(n + 3) / 4, 256, 0, stream>>>(csr_src, nstart, cnt, gbuf, dis, b2, hbuf, n);

    // ---- layer 3 ----
    gemm3<<<(n + 127) / 128, 128, 0, stream>>>(hbuf, W3, dis, gbuf, n);
    gather3<<<(n + 3) / 4, 256, 0, stream>>>(csr_src, nstart, cnt, gbuf, dis, b3, out, n);
}

// Round 8
// 380.326 us; speedup vs baseline: 4.3336x; 1.0746x over previous
//
#include <hip/hip_runtime.h>

// ---- bf16 helpers (manual, finite-value RNE) ----
static __device__ __forceinline__ unsigned short f2bf(float f) {
    unsigned u = __float_as_uint(f);
    unsigned r = (u + 0x7FFF + ((u >> 16) & 1)) >> 16;
    return (unsigned short)r;
}
static __device__ __forceinline__ float bf2f(unsigned short h) {
    return __uint_as_float(((unsigned)h) << 16);
}

// ==================== bucket binning ====================
#define BKT_SHIFT 7
#define BKT_NODES 128
#define CHUNK 32768  // edges per hist/scatter block (512 thr x 64)

__global__ __launch_bounds__(512) void hist_k(const int* __restrict__ dst, int* __restrict__ histG,
                                              int B, int NB, int E) {
    __shared__ int hist[1024];
    int tid = threadIdx.x;
    for (int i = tid; i < NB; i += 512) hist[i] = 0;
    __syncthreads();
    int base = blockIdx.x * CHUNK;
    for (int i = tid; i < CHUNK; i += 512) {
        int e = base + i;
        if (e >= E) break;
        atomicAdd(&hist[dst[e] >> BKT_SHIFT], 1);
    }
    __syncthreads();
    for (int i = tid; i < NB; i += 512) histG[(size_t)i * B + blockIdx.x] = hist[i];
}

__global__ __launch_bounds__(512) void scatter_k(const int* __restrict__ src, const int* __restrict__ dst,
                                                 const int* __restrict__ scanG, int* __restrict__ pairs,
                                                 int B, int NB, int E) {
    __shared__ int sbase[1024];
    __shared__ int scnt[1024];
    int tid = threadIdx.x;
    for (int i = tid; i < NB; i += 512) {
        sbase[i] = scanG[(size_t)i * B + blockIdx.x];
        scnt[i] = 0;
    }
    __syncthreads();
    int base = blockIdx.x * CHUNK;
    for (int i = tid; i < CHUNK; i += 512) {
        int e = base + i;
        if (e >= E) break;
        int d = dst[e], s = src[e];
        int b = d >> BKT_SHIFT;
        int r = atomicAdd(&scnt[b], 1);
        pairs[sbase[b] + r] = (s << BKT_SHIFT) | (d & (BKT_NODES - 1));
    }
}

// ==================== scan (exclusive), 256 thr x 8 = 2048 elems/block ====================
#define SCAN_VPT 8
#define SCAN_ELEMS 2048

__global__ __launch_bounds__(256) void scan1(const int* __restrict__ in, int* __restrict__ out,
                                             int* __restrict__ blksum, int n) {
    __shared__ int sh[256];
    int base = blockIdx.x * SCAN_ELEMS + threadIdx.x * SCAN_VPT;
    int v[SCAN_VPT];
    int sum = 0;
    #pragma unroll
    for (int j = 0; j < SCAN_VPT; ++j) {
        v[j] = (base + j < n) ? in[base + j] : 0;
        sum += v[j];
    }
    sh[threadIdx.x] = sum;
    __syncthreads();
    for (int off = 1; off < 256; off <<= 1) {
        int t = (threadIdx.x >= off) ? sh[threadIdx.x - off] : 0;
        __syncthreads();
        sh[threadIdx.x] += t;
        __syncthreads();
    }
    if (threadIdx.x == 255) blksum[blockIdx.x] = sh[255];
    int run = sh[threadIdx.x] - sum;
    #pragma unroll
    for (int j = 0; j < SCAN_VPT; ++j) {
        if (base + j < n) out[base + j] = run;
        run += v[j];
    }
}

__global__ __launch_bounds__(256) void scan2(int* __restrict__ blksum, int nb) {
    __shared__ int sh[256];
    int t = threadIdx.x;
    int v = (t < nb) ? blksum[t] : 0;
    sh[t] = v;
    __syncthreads();
    for (int off = 1; off < 256; off <<= 1) {
        int u = (t >= off) ? sh[t - off] : 0;
        __syncthreads();
        sh[t] += u;
        __syncthreads();
    }
    if (t < nb) blksum[t] = sh[t] - v;
}

__global__ void scan3(int* __restrict__ out, const int* __restrict__ blksum, int n) {
    int i = blockIdx.x * blockDim.x + threadIdx.x;
    if (i < n) out[i] += blksum[i >> 11];
}

// ==================== within-bucket counting sort -> dst-sorted CSR + degree/dis ====================
#define SORT_CAP 8192  // mean bucket size 4096, tight concentration -> 8192 unreachable

__global__ __launch_bounds__(512) void sort_bucket(const int* __restrict__ pairs,
        const int* __restrict__ scanG, int B, int NB,
        int* __restrict__ csr_src, int* __restrict__ node_start,
        int* __restrict__ cnt, float* __restrict__ dis, int n, int E) {
    __shared__ int keys[SORT_CAP];
    __shared__ int lcnt[BKT_NODES];
    __shared__ int lscan[BKT_NODES];
    __shared__ int lfill[BKT_NODES];
    int bkt = blockIdx.x, tid = threadIdx.x;
    int e0 = scanG[(size_t)bkt * B];
    int e1 = (bkt + 1 < NB) ? scanG[(size_t)(bkt + 1) * B] : E;
    int m = e1 - e0;
    if (tid < BKT_NODES) { lcnt[tid] = 0; lfill[tid] = 0; }
    __syncthreads();
    for (int i = tid; i < m; i += 512) {
        int k = pairs[e0 + i];
        if (i < SORT_CAP) keys[i] = k;
        atomicAdd(&lcnt[k & (BKT_NODES - 1)], 1);
    }
    __syncthreads();
    if (tid == 0) {
        int run = 0;
        for (int i = 0; i < BKT_NODES; ++i) { lscan[i] = run; run += lcnt[i]; }
    }
    __syncthreads();
    int nb0 = bkt << BKT_SHIFT;
    if (tid < BKT_NODES && nb0 + tid < n) {
        int deg = lcnt[tid];
        node_start[nb0 + tid] = e0 + lscan[tid];
        cnt[nb0 + tid] = deg;
        dis[nb0 + tid] = rsqrtf((float)deg + 1.0f);
    }
    for (int i = tid; i < m; i += 512) {
        int k = (i < SORT_CAP) ? keys[i] : pairs[e0 + i];
        int d = k & (BKT_NODES - 1);
        int pos = lscan[d] + atomicAdd(&lfill[d], 1);
        csr_src[e0 + pos] = k >> BKT_SHIFT;
    }
}

// ==================== GEMMs (epilogue scales row by dis[node], writes bf16 g) ====================

__global__ __launch_bounds__(128) void gemm1(const float* __restrict__ x, const float* __restrict__ W,
                                             const float* __restrict__ dis, unsigned short* __restrict__ g, int n) {
    __shared__ float ws[32 * 32];
    __shared__ float xs[128][33];
    int tid = threadIdx.x;
    int node0 = blockIdx.x * 128;
    int node = node0 + tid;
    float acc[32];
    #pragma unroll
    for (int c = 0; c < 32; ++c) acc[c] = 0.f;

    for (int k0 = 0; k0 < 512; k0 += 32) {
        __syncthreads();
        #pragma unroll
        for (int r = 0; r < 2; ++r) {
            int fi = tid + r * 128;
            int k = fi >> 3, c4 = fi & 7;
            float4 wv = *(const float4*)(W + (size_t)(k0 + k) * 32 + c4 * 4);
            *((float4*)(ws + k * 32 + c4 * 4)) = wv;
        }
        #pragma unroll
        for (int r = 0; r < 8; ++r) {
            int fi = tid + r * 128;
            int nd = fi >> 3, k4 = fi & 7;
            int gn = min(node0 + nd, n - 1);
            float4 xv = *(const float4*)(x + (size_t)gn * 512 + k0 + k4 * 4);
            xs[nd][k4 * 4 + 0] = xv.x;
            xs[nd][k4 * 4 + 1] = xv.y;
            xs[nd][k4 * 4 + 2] = xv.z;
            xs[nd][k4 * 4 + 3] = xv.w;
        }
        __syncthreads();
        #pragma unroll
        for (int k = 0; k < 32; ++k) {
            float xv = xs[tid][k];
            #pragma unroll
            for (int c = 0; c < 32; ++c) acc[c] += xv * ws[k * 32 + c];
        }
    }
    if (node < n) {
        float dv = dis[node];
        ushort4 pk[4];
        #pragma unroll
        for (int q = 0; q < 4; ++q) {
            pk[q].x = f2bf(acc[q * 4 + 0] * dv);
            pk[q].y = f2bf(acc[q * 4 + 1] * dv);
            pk[q].z = f2bf(acc[q * 4 + 2] * dv);
            pk[q].w = f2bf(acc[q * 4 + 3] * dv);
        }
        ushort4* o4 = (ushort4*)(g + (size_t)node * 32);
        #pragma unroll
        for (int q = 0; q < 4; ++q) o4[q * 2] = pk[q];  // wait: layout fix below
        // NOTE: acc[16..31] handled in second half
        #pragma unroll
        for (int q = 0; q < 4; ++q) {
            ushort4 p2;
            p2.x = f2bf(acc[16 + q * 4 + 0] * dv);
            p2.y = f2bf(acc[16 + q * 4 + 1] * dv);
            p2.z = f2bf(acc[16 + q * 4 + 2] * dv);
            p2.w = f2bf(acc[16 + q * 4 + 3] * dv);
            o4[4 + q] = p2;
        }
        // fix first half to correct slots (o4[0..3])
        #pragma unroll
        for (int q = 0; q < 4; ++q) o4[q] = pk[q];
    }
}

__global__ __launch_bounds__(128) void gemm2(const float* __restrict__ xin, const float* __restrict__ W,
                                             const float* __restrict__ dis, unsigned short* __restrict__ g, int n) {
    __shared__ float ws[32 * 16];
    __shared__ float xs[128][33];
    int tid = threadIdx.x;
    int node0 = blockIdx.x * 128;
    int node = node0 + tid;
    {
        int k = tid >> 2, c4 = tid & 3;
        float4 wv = *(const float4*)(W + (size_t)k * 16 + c4 * 4);
        *((float4*)(ws + k * 16 + c4 * 4)) = wv;
    }
    #pragma unroll
    for (int r = 0; r < 8; ++r) {
        int fi = tid + r * 128;
        int nd = fi >> 3, k4 = fi & 7;
        int gn = min(node0 + nd, n - 1);
        float4 xv = *(const float4*)(xin + (size_t)gn * 32 + k4 * 4);
        xs[nd][k4 * 4 + 0] = xv.x;
        xs[nd][k4 * 4 + 1] = xv.y;
        xs[nd][k4 * 4 + 2] = xv.z;
        xs[nd][k4 * 4 + 3] = xv.w;
    }
    __syncthreads();
    float acc[16];
    #pragma unroll
    for (int c = 0; c < 16; ++c) acc[c] = 0.f;
    #pragma unroll
    for (int k = 0; k < 32; ++k) {
        float xv = xs[tid][k];
        #pragma unroll
        for (int c = 0; c < 16; ++c) acc[c] += xv * ws[k * 16 + c];
    }
    if (node < n) {
        float dv = dis[node];
        ushort4* o4 = (ushort4*)(g + (size_t)node * 16);
        #pragma unroll
        for (int q = 0; q < 4; ++q) {
            ushort4 p;
            p.x = f2bf(acc[q * 4 + 0] * dv);
            p.y = f2bf(acc[q * 4 + 1] * dv);
            p.z = f2bf(acc[q * 4 + 2] * dv);
            p.w = f2bf(acc[q * 4 + 3] * dv);
            o4[q] = p;
        }
    }
}

__global__ __launch_bounds__(128) void gemm3(const float* __restrict__ xin, const float* __restrict__ W,
                                             const float* __restrict__ dis, unsigned short* __restrict__ g, int n) {
    __shared__ float ws[16 * 16];
    __shared__ float xs[128][17];
    int tid = threadIdx.x;
    int node0 = blockIdx.x * 128;
    int node = node0 + tid;
    #pragma unroll
    for (int fi = 0; fi < 2; ++fi) {
        int i = tid + fi * 128;
        int k = i >> 4, c = i & 15;
        ws[i] = (c < 11) ? W[(size_t)k * 11 + c] : 0.f;
    }
    #pragma unroll
    for (int r = 0; r < 4; ++r) {
        int fi = tid + r * 128;
        int nd = fi >> 2, k4 = fi & 3;
        int gn = min(node0 + nd, n - 1);
        float4 xv = *(const float4*)(xin + (size_t)gn * 16 + k4 * 4);
        xs[nd][k4 * 4 + 0] = xv.x;
        xs[nd][k4 * 4 + 1] = xv.y;
        xs[nd][k4 * 4 + 2] = xv.z;
        xs[nd][k4 * 4 + 3] = xv.w;
    }
    __syncthreads();
    float acc[16];
    #pragma unroll
    for (int c = 0; c < 16; ++c) acc[c] = 0.f;
    #pragma unroll
    for (int k = 0; k < 16; ++k) {
        float xv = xs[tid][k];
        #pragma unroll
        for (int c = 0; c < 16; ++c) acc[c] += xv * ws[k * 16 + c];
    }
    if (node < n) {
        float dv = dis[node];
        ushort4* o4 = (ushort4*)(g + (size_t)node * 16);
        #pragma unroll
        for (int q = 0; q < 4; ++q) {
            ushort4 p;
            p.x = f2bf(acc[q * 4 + 0] * dv);
            p.y = f2bf(acc[q * 4 + 1] * dv);
            p.z = f2bf(acc[q * 4 + 2] * dv);
            p.w = f2bf(acc[q * 4 + 3] * dv);
            o4[q] = p;
        }
    }
}

// ==================== node-parallel CSR gather (one wave per node), bf16 g ====================
// out[v] = relu?((sum_{e in CSR(v)} g[src] + g[v]) * dis[v] + b)   [f32 out]

template<int F, int LOGF, bool RELU>
__global__ __launch_bounds__(256) void gather_csr(const int* __restrict__ csr_src,
        const int* __restrict__ start, const int* __restrict__ cnt,
        const unsigned short* __restrict__ g, const float* __restrict__ dis,
        const float* __restrict__ bias, float* __restrict__ out, int n) {
    int node = blockIdx.x * 4 + (threadIdx.x >> 6);
    if (node >= n) return;
    int lane = threadIdx.x & 63;
    int f = lane & (F - 1);
    int j = lane >> LOGF;
    const int EPI = 64 / F;
    int i0 = start[node], i1 = i0 + cnt[node];
    float acc = 0.f;
    int i = i0 + j;
    // 4x independent-chain unroll for MLP
    for (; i + 3 * EPI < i1; i += 4 * EPI) {
        int s1 = csr_src[i];
        int s2 = csr_src[i + EPI];
        int s3 = csr_src[i + 2 * EPI];
        int s4 = csr_src[i + 3 * EPI];
        unsigned short v1 = g[(size_t)s1 * F + f];
        unsigned short v2 = g[(size_t)s2 * F + f];
        unsigned short v3 = g[(size_t)s3 * F + f];
        unsigned short v4 = g[(size_t)s4 * F + f];
        acc += bf2f(v1) + bf2f(v2) + bf2f(v3) + bf2f(v4);
    }
    for (; i < i1; i += EPI) acc += bf2f(g[(size_t)csr_src[i] * F + f]);
    #pragma unroll
    for (int m = F; m < 64; m <<= 1) acc += __shfl_xor(acc, m);
    float val = (acc + bf2f(g[(size_t)node * F + f])) * dis[node] + bias[f];
    if (RELU) val = fmaxf(val, 0.f);
    if (lane < F) out[(size_t)node * F + f] = val;
}

// layer 3 gather + fused log_softmax (stride 16 in, 11 classes out)
__global__ __launch_bounds__(256) void gather3(const int* __restrict__ csr_src,
        const int* __restrict__ start, const int* __restrict__ cnt,
        const unsigned short* __restrict__ g, const float* __restrict__ dis,
        const float* __restrict__ bias, float* __restrict__ out, int n) {
    int node = blockIdx.x * 4 + (threadIdx.x >> 6);
    if (node >= n) return;
    int lane = threadIdx.x & 63;
    int f = lane & 15;
    int j = lane >> 4;
    int i0 = start[node], i1 = i0 + cnt[node];
    float acc = 0.f;
    int i = i0 + j;
    for (; i + 12 < i1; i += 16) {
        int s1 = csr_src[i];
        int s2 = csr_src[i + 4];
        int s3 = csr_src[i + 8];
        int s4 = csr_src[i + 12];
        unsigned short v1 = g[(size_t)s1 * 16 + f];
        unsigned short v2 = g[(size_t)s2 * 16 + f];
        unsigned short v3 = g[(size_t)s3 * 16 + f];
        unsigned short v4 = g[(size_t)s4 * 16 + f];
        acc += bf2f(v1) + bf2f(v2) + bf2f(v3) + bf2f(v4);
    }
    for (; i < i1; i += 4) acc += bf2f(g[(size_t)csr_src[i] * 16 + f]);
    acc += __shfl_xor(acc, 16);
    acc += __shfl_xor(acc, 32);
    float val = (acc + bf2f(g[(size_t)node * 16 + f])) * dis[node] + ((f < 11) ? bias[f] : 0.f);
    float vm = (f < 11) ? val : -3.0e38f;
    #pragma unroll
    for (int m = 1; m < 16; m <<= 1) vm = fmaxf(vm, __shfl_xor(vm, m));
    float ex = (f < 11) ? __expf(val - vm) : 0.f;
    float sum = ex;
    #pragma unroll
    for (int m = 1; m < 16; m <<= 1) sum += __shfl_xor(sum, m);
    if (lane < 11) out[(size_t)node * 11 + f] = val - (__logf(sum) + vm);
}

// ==================== launch ====================

extern "C" void kernel_launch(void* const* d_in, const int* in_sizes, int n_in,
                              void* d_out, int out_size, void* d_ws, size_t ws_size,
                              hipStream_t stream) {
    const float* x  = (const float*)d_in[0];
    const int*   ei = (const int*)d_in[1];
    const float* W1 = (const float*)d_in[2];
    const float* b1 = (const float*)d_in[3];
    const float* W2 = (const float*)d_in[4];
    const float* b2 = (const float*)d_in[5];
    const float* W3 = (const float*)d_in[6];
    const float* b3 = (const float*)d_in[7];
    float* out = (float*)d_out;

    const int n = in_sizes[0] / 512;
    const int E = in_sizes[1] / 2;
    const int* src = ei;
    const int* dst = ei + E;

    const int NB = (n + BKT_NODES - 1) >> BKT_SHIFT;      // buckets (782)
    const int B  = (E + CHUNK - 1) / CHUNK;               // hist/scatter blocks (98)
    const int NBB = NB * B;                               // flattened histogram
    const int nb_scan = (NBB + SCAN_ELEMS - 1) / SCAN_ELEMS;

    // workspace layout (4B elements)
    int* ws0 = (int*)d_ws;
    size_t off = 0;
    int*   cnt     = ws0 + off; off += (size_t)n;
    float* dis     = (float*)(ws0 + off); off += (size_t)n;
    int*   nstart  = ws0 + off; off += (size_t)n;
    int*   scanG   = ws0 + off; off += (size_t)NBB;
    int*   blksum  = ws0 + off; off += 256;
    int*   pairs   = ws0 + off; off += (size_t)E;
    int*   csr_src = ws0 + off; off += (size_t)E;
    unsigned short* gbuf = (unsigned short*)(ws0 + off); off += (size_t)n * 16;  // n*32 bf16
    float* hbuf    = (float*)(ws0 + off); off += (size_t)n * 32;
    int*   histG   = (int*)hbuf;  // alias: histG dead before hbuf first written

    // ---- bucket binning + within-bucket counting sort -> dst-sorted CSR + deg/dis ----
    hist_k<<<B, 512, 0, stream>>>(dst, histG, B, NB, E);
    scan1<<<nb_scan, 256, 0, stream>>>(histG, scanG, blksum, NBB);
    scan2<<<1, 256, 0, stream>>>(blksum, nb_scan);
    scan3<<<(NBB + 255) / 256, 256, 0, stream>>>(scanG, blksum, NBB);
    scatter_k<<<B, 512, 0, stream>>>(src, dst, scanG, pairs, B, NB, E);
    sort_bucket<<<NB, 512, 0, stream>>>(pairs, scanG, B, NB, csr_src, nstart, cnt, dis, n, E);

    // ---- layer 1 ----
    gemm1<<<(n + 127) / 128, 128, 0, stream>>>(x, W1, dis, gbuf, n);
    gather_csr<32, 5, true><<<(n + 3) / 4, 256, 0, stream>>>(csr_src, nstart, cnt, gbuf, dis, b1, hbuf, n);

    // ---- layer 2 ----
    gemm2<<<(n + 127) / 128, 128, 0, stream>>>(hbuf, W2, dis, gbuf, n);
    gather_csr<16, 4, true><<<(n + 3) / 4, 256, 0, stream>>>(csr_src, nstart, cnt, gbuf, dis, b2, hbuf, n);

    // ---- layer 3 ----
    gemm3<<<(n + 127) / 128, 128, 0, stream>>>(hbuf, W3, dis, gbuf, n);
    gather3<<<(n + 3) / 4, 256, 0, stream>>>(csr_src, nstart, cnt, gbuf, dis, b3, out, n);
}